// Round 9
// baseline (110.521 us; speedup 1.0000x reference)
//
#include <hip/hip_runtime.h>
#include <math.h>

#define BS 32
#define NT 50
#define NC 80
#define H 76
#define W 76
#define HW (H*W)
#define NA (5+NC)
#define SIGMA 8.0f
#define YBLK 23          // ceil(HW/256)
#define NBLK (BS*YBLK)   // 736

// _clog: clip(log(clip(p,1e-12,1)), -100, 0)
__device__ __forceinline__ float clog_(float p){
    p = fminf(fmaxf(p, 1e-12f), 1.0f);
    float l = logf(p);
    return fminf(fmaxf(l, -100.0f), 0.0f);
}

__device__ __forceinline__ float sigmoid_(float v){
    return 1.0f / (1.0f + expf(-v));
}

// ---------------- Kernel 1: prep + per-cell loss (2 threads/cell split-K) ----------------
// partials layout: partials[j*NBLK + bid], j in 0..5 = {x,y,w,h,conf,tcls}
__global__ __launch_bounds__(512) void yolo_main(
    const float* __restrict__ input,
    const float* __restrict__ targets,
    float*       __restrict__ partials,
    int*         __restrict__ counts)
{
    const int b    = blockIdx.x;
    const int yb   = blockIdx.y;
    const int tid  = threadIdx.x;
    const int cidx = tid & 255;        // cell index within block
    const int half = tid >> 8;         // 0/1: which parity of targets to scan
    const int bid  = b * YBLK + yb;

    // ---- in-block target prep (redundant per block; tiny) ----
    __shared__ float4 s_box[NT];       // gx1,gy1,gx2,gy2 (compacted)
    __shared__ int    s_cellc[NT];     // cell id (compacted)
    __shared__ float4 s_rest[NT];      // tx,ty,tw,th
    __shared__ float2 s_sc[NT];        // scale, cls
    __shared__ int    s_cell[NT];
    __shared__ unsigned char s_valid[NT];
    __shared__ int    s_count;

    if (tid == 0) s_count = 0;

    float cls=0.f, xx=0.f, yy=0.f, ww=0.f, hh=0.f;
    bool valid = false;
    int cell0 = 0;
    if (tid < NT){
        const float* p = targets + ((size_t)b*NT + tid)*5;
        cls = p[0]; xx = p[1]; yy = p[2]; ww = p[3]; hh = p[4];
        valid = ((cls + xx + yy + ww + hh) != 0.0f);
        float gx = xx * (float)W, gy = yy * (float)H;
        int gi = min(max((int)gx, 0), W-1);
        int gj = min(max((int)gy, 0), H-1);
        cell0 = gj*W + gi;
        s_cell[tid]  = cell0;
        s_valid[tid] = valid ? 1 : 0;
    }
    __syncthreads();
    if (tid < NT && valid){
        bool dup = false;
        for (int u = 0; u < tid; ++u)
            if (s_valid[u] && s_cell[u] == cell0) dup = true;
        if (!dup){
            int idx = atomicAdd(&s_count, 1);   // LDS atomic — cheap
            float gx = xx*(float)W, gy = yy*(float)H;
            float gw = ww*(float)W, gh = hh*(float)H;
            int gi = min(max((int)gx, 0), W-1);
            int gj = min(max((int)gy, 0), H-1);
            s_box[idx]  = make_float4(gx - gw*0.5f, gy - gh*0.5f,
                                      gx + gw*0.5f, gy + gh*0.5f);
            s_cellc[idx]= cell0;
            s_rest[idx] = make_float4(gx - (float)gi, gy - (float)gj,
                                      logf(gw/SIGMA + 1e-16f),
                                      logf(gh/SIGMA + 1e-16f));
            s_sc[idx]   = make_float2(2.0f - ww*hh,
                                      (float)min(max((int)cls, 0), NC-1));
        }
    }
    __syncthreads();
    const int nb = s_count;

    float lx=0.f, ly=0.f, lw=0.f, lh=0.f, lc=0.f, lt=0.f;

    const int cellLo = yb * 256;
    const int cellHi = (cellLo + 256 < HW) ? cellLo + 256 : HW;
    const float* binp = input + (size_t)b*NA*HW;

    // ---- cooperative tcls: lane c (<80, half 0 only) loads class channel c ----
    for (int t = 0; t < nb; ++t){
        int q = s_cellc[t];
        if (q >= cellLo && q < cellHi && tid < NC){
            float pc = sigmoid_(binp[(size_t)(5+tid)*HW + q]);
            int cidx2 = (int)s_sc[t].y;                  // broadcast LDS read
            lt += (tid == cidx2) ? -clog_(pc) : -clog_(1.f - pc);
        }
    }

    // ---- per-cell loss, split-K over targets between the two halves ----
    __shared__ int           s_myt2[512];
    __shared__ unsigned char s_ig2[512];

    const int cell = cellLo + cidx;
    const bool incell = (cell < HW);
    bool ignore = false;
    int  myt = -1;
    float vx=0.f, vy=0.f, vw=0.f, vh=0.f, vc=0.f;
    float x=0.f, y=0.f, conf=0.f;

    if (incell){
        const float* base = binp + cell;
        vx = base[0];
        vy = base[HW];
        vw = base[2*HW];
        vh = base[3*HW];
        vc = base[4*HW];
        x    = sigmoid_(vx);
        y    = sigmoid_(vy);
        conf = sigmoid_(vc);
        int i = cell / W, j = cell - i*W;
        float pw = expf(vw) * SIGMA;
        float ph = expf(vh) * SIGMA;
        float px = x + (float)j;
        float py = y + (float)i;
        float px1 = px - pw*0.5f, px2 = px + pw*0.5f;
        float py1 = py - ph*0.5f, py2 = py + ph*0.5f;
        float parea = pw * ph;

        for (int t = half; t < nb; t += 2){
            float4 bx = s_box[t];               // broadcast ds_read_b128
            float garea = (bx.z - bx.x) * (bx.w - bx.y);
            float iw = fminf(bx.z, px2) - fmaxf(bx.x, px1);
            float ih = fminf(bx.w, py2) - fmaxf(bx.y, py1);
            iw = fmaxf(iw, 0.f); ih = fmaxf(ih, 0.f);
            float inter = iw * ih;
            // iou >= 0.5  <=>  inter >= 0.5*(garea + parea - inter + eps)
            ignore = ignore || (inter >= 0.5f*(garea + parea - inter + 1e-16f));
            if (s_cellc[t] == cell) myt = t;
        }
    }
    s_myt2[tid] = myt;
    s_ig2[tid]  = ignore ? 1 : 0;
    __syncthreads();

    if (half == 0 && incell){
        ignore = ignore || (s_ig2[tid + 256] != 0);
        myt    = max(myt, s_myt2[tid + 256]);

        if (myt >= 0){
            float4 r = s_rest[myt];
            float scale = s_sc[myt].x;
            lx = scale * (-(r.x*clog_(x) + (1.f-r.x)*clog_(1.f-x)));
            ly = scale * (-(r.y*clog_(y) + (1.f-r.y)*clog_(1.f-y)));
            float dw = fabsf(vw - r.z);
            lw = scale * (dw < 1.f ? 0.5f*dw*dw : dw - 0.5f);
            float dh = fabsf(vh - r.w);
            lh = scale * (dh < 1.f ? 0.5f*dh*dh : dh - 0.5f);
            lc = -clog_(conf);
        } else if (!ignore){
            lc = 0.5f * (-clog_(1.0f - conf));
        }
    }

    // ---- block reduction: wave shuffle (8 waves), then cross-wave via LDS ----
    #pragma unroll
    for (int off = 32; off > 0; off >>= 1){
        lx += __shfl_down(lx, off);
        ly += __shfl_down(ly, off);
        lw += __shfl_down(lw, off);
        lh += __shfl_down(lh, off);
        lc += __shfl_down(lc, off);
        lt += __shfl_down(lt, off);
    }
    __shared__ float s_red[8*6];
    if ((tid & 63) == 0){
        int wv = tid >> 6;
        s_red[wv*6+0] = lx; s_red[wv*6+1] = ly; s_red[wv*6+2] = lw;
        s_red[wv*6+3] = lh; s_red[wv*6+4] = lc; s_red[wv*6+5] = lt;
    }
    __syncthreads();
    if (tid < 6){
        float v = 0.f;
        #pragma unroll
        for (int wv = 0; wv < 8; ++wv) v += s_red[wv*6 + tid];
        partials[tid*NBLK + bid] = v;          // block-unique slot, no atomics
    }
    if (yb == 0 && tid == 0) counts[b] = nb;
}

// ---------------- Kernel 2: final reduce over 736 blocks + n_obj + output ----------------
__global__ __launch_bounds__(256) void finalize_k(
    const float* __restrict__ partials,
    const int*   __restrict__ counts,
    float*       __restrict__ out)
{
    int tid = threadIdx.x;
    float loc[6] = {0,0,0,0,0,0};
    for (int k = tid; k < NBLK; k += 256){
        #pragma unroll
        for (int j = 0; j < 6; ++j) loc[j] += partials[j*NBLK + k];
    }
    float nloc = (tid < BS) ? (float)counts[tid] : 0.f;

    #pragma unroll
    for (int off = 32; off > 0; off >>= 1){
        #pragma unroll
        for (int j = 0; j < 6; ++j) loc[j] += __shfl_down(loc[j], off);
        nloc += __shfl_down(nloc, off);
    }
    __shared__ float s_red[4*7];
    if ((tid & 63) == 0){
        int wv = tid >> 6;
        #pragma unroll
        for (int j = 0; j < 6; ++j) s_red[wv*7+j] = loc[j];
        s_red[wv*7+6] = nloc;
    }
    __syncthreads();
    if (tid == 0){
        float s[7];
        #pragma unroll
        for (int j = 0; j < 7; ++j)
            s[j] = s_red[j] + s_red[7+j] + s_red[14+j] + s_red[21+j];
        float n = s[6];
        float inv = (n > 0.f) ? (1.0f / n) : 0.0f;
        float lx = s[0]*inv, ly = s[1]*inv, lw = s[2]*inv, lh = s[3]*inv;
        float lconf = s[4]*inv;
        float ltcls = (n > 0.f) ? s[5]*inv : 0.0f;
        out[0] = lx + ly + lw + lh + lconf + ltcls;
        out[1] = lx;
        out[2] = ly;
        out[3] = lw;
        out[4] = lh;
        out[5] = lconf;
        out[6] = ltcls;
    }
}

extern "C" void kernel_launch(void* const* d_in, const int* in_sizes, int n_in,
                              void* d_out, int out_size, void* d_ws, size_t ws_size,
                              hipStream_t stream) {
    const float* input   = (const float*)d_in[0];
    const float* targets = (const float*)d_in[1];
    float* out = (float*)d_out;

    // ws layout: [0 .. 6*NBLK*4) partials | then counts[32]
    float* partials = (float*)d_ws;
    int*   counts   = (int*)((char*)d_ws + 6*NBLK*sizeof(float));

    dim3 grid(BS, YBLK);
    yolo_main<<<grid, dim3(512), 0, stream>>>(input, targets, partials, counts);
    finalize_k<<<1, dim3(256), 0, stream>>>(partials, counts, out);
}

// Round 10
// 107.309 us; speedup vs baseline: 1.0299x; 1.0299x over previous
//
#include <hip/hip_runtime.h>
#include <math.h>

#define BS 32
#define NT 50
#define NC 80
#define H 76
#define W 76
#define HW (H*W)
#define NA (5+NC)
#define SIGMA 8.0f
#define YBLK 23          // ceil(HW/256)
#define NBLK (BS*YBLK)   // 736

// _clog: clip(log(clip(p,1e-12,1)), -100, 0)
__device__ __forceinline__ float clog_(float p){
    p = fminf(fmaxf(p, 1e-12f), 1.0f);
    float l = logf(p);
    return fminf(fmaxf(l, -100.0f), 0.0f);
}

__device__ __forceinline__ float sigmoid_(float v){
    return 1.0f / (1.0f + expf(-v));
}

// ---------------- Kernel 1: prep + per-cell loss + cooperative tcls ----------------
// Best measured config (R8: 108.07 us, absmax 0.0).
// Session findings baked into this structure:
//  - no global atomics in the hot path (R1->R2: 332->128 us; 17k same-line
//    device-scope atomics cost ~220 us on 8-XCD gfx950)
//  - no per-block __threadfence (R3: +38 us — device-scope fences from all
//    blocks serialize at L2 writeback)
//  - cooperative tcls: lanes 0..79 gather all 80 class channels at once
//    (R4: 128->108 us; divergent-lane serial loads were the straggler)
//  - inline prep beats hoisted prep + extra dispatch (R5 neutral)
//  - fast-math, 3-cell ILP, 2x-wave split-K all neutral/regressions (R6-R9)
// partials layout: partials[j*NBLK + bid], j in 0..5 = {x,y,w,h,conf,tcls}
__global__ __launch_bounds__(256) void yolo_main(
    const float* __restrict__ input,
    const float* __restrict__ targets,
    float*       __restrict__ partials,
    int*         __restrict__ counts)
{
    const int b   = blockIdx.x;
    const int yb  = blockIdx.y;
    const int tid = threadIdx.x;
    const int bid = b * YBLK + yb;

    // ---- in-block target prep (redundant per block; tiny) ----
    __shared__ float4 s_box[NT];         // gx1,gy1,gx2,gy2 (compacted)
    __shared__ int    s_cellc[NT];       // cell id (compacted)
    __shared__ float4 s_rest[NT];        // tx,ty,tw,th
    __shared__ float2 s_sc[NT];          // scale, cls
    __shared__ int    s_cell[NT];
    __shared__ unsigned char s_valid[NT];
    __shared__ int    s_count;

    if (tid == 0) s_count = 0;

    float cls=0.f, xx=0.f, yy=0.f, ww=0.f, hh=0.f;
    bool valid = false;
    int cell0 = 0;
    if (tid < NT){
        const float* p = targets + ((size_t)b*NT + tid)*5;
        cls = p[0]; xx = p[1]; yy = p[2]; ww = p[3]; hh = p[4];
        valid = ((cls + xx + yy + ww + hh) != 0.0f);
        float gx = xx * (float)W, gy = yy * (float)H;
        int gi = min(max((int)gx, 0), W-1);
        int gj = min(max((int)gy, 0), H-1);
        cell0 = gj*W + gi;
        s_cell[tid]  = cell0;
        s_valid[tid] = valid ? 1 : 0;
    }
    __syncthreads();
    if (tid < NT && valid){
        bool dup = false;
        for (int u = 0; u < tid; ++u)
            if (s_valid[u] && s_cell[u] == cell0) dup = true;
        if (!dup){
            int idx = atomicAdd(&s_count, 1);   // LDS atomic — cheap
            float gx = xx*(float)W, gy = yy*(float)H;
            float gw = ww*(float)W, gh = hh*(float)H;
            int gi = min(max((int)gx, 0), W-1);
            int gj = min(max((int)gy, 0), H-1);
            s_box[idx]  = make_float4(gx - gw*0.5f, gy - gh*0.5f,
                                      gx + gw*0.5f, gy + gh*0.5f);
            s_cellc[idx]= cell0;
            s_rest[idx] = make_float4(gx - (float)gi, gy - (float)gj,
                                      logf(gw/SIGMA + 1e-16f),
                                      logf(gh/SIGMA + 1e-16f));
            s_sc[idx]   = make_float2(2.0f - ww*hh,
                                      (float)min(max((int)cls, 0), NC-1));
        }
    }
    __syncthreads();
    const int nb = s_count;

    float lx=0.f, ly=0.f, lw=0.f, lh=0.f, lc=0.f, lt=0.f;

    const int cellLo = yb * 256;
    const int cellHi = (cellLo + 256 < HW) ? cellLo + 256 : HW;
    const float* binp = input + (size_t)b*NA*HW;

    // ---- cooperative tcls: for each object in this block's cell range,
    // lane c (<80) loads class channel c -> 80 strided loads in flight at once.
    for (int t = 0; t < nb; ++t){
        int q = s_cellc[t];
        if (q >= cellLo && q < cellHi && tid < NC){      // wave-uniform except lane split
            float pc = sigmoid_(binp[(size_t)(5+tid)*HW + q]);
            int cidx = (int)s_sc[t].y;                   // broadcast LDS read
            lt += (tid == cidx) ? -clog_(pc) : -clog_(1.f - pc);
        }
    }

    // ---- per-cell loss (no class loop here) ----
    const int cell = cellLo + tid;
    if (cell < HW){
        const float* base = binp + cell;
        float vx = base[0];
        float vy = base[HW];
        float vw = base[2*HW];
        float vh = base[3*HW];
        float vc = base[4*HW];
        float x    = sigmoid_(vx);
        float y    = sigmoid_(vy);
        float conf = sigmoid_(vc);
        int i = cell / W, j = cell - i*W;
        float pw = expf(vw) * SIGMA;
        float ph = expf(vh) * SIGMA;
        float px = x + (float)j;
        float py = y + (float)i;
        float px1 = px - pw*0.5f, px2 = px + pw*0.5f;
        float py1 = py - ph*0.5f, py2 = py + ph*0.5f;
        float parea = pw * ph;

        bool ignore = false;
        int myt = -1;
        for (int t = 0; t < nb; ++t){
            float4 bx = s_box[t];               // broadcast ds_read_b128
            float garea = (bx.z - bx.x) * (bx.w - bx.y);
            float iw = fminf(bx.z, px2) - fmaxf(bx.x, px1);
            float ih = fminf(bx.w, py2) - fmaxf(bx.y, py1);
            iw = fmaxf(iw, 0.f); ih = fmaxf(ih, 0.f);
            float inter = iw * ih;
            // iou >= 0.5  <=>  inter >= 0.5*(garea + parea - inter + eps)
            ignore = ignore || (inter >= 0.5f*(garea + parea - inter + 1e-16f));
            if (s_cellc[t] == cell) myt = t;
        }

        if (myt >= 0){
            float4 r = s_rest[myt];
            float scale = s_sc[myt].x;
            lx = scale * (-(r.x*clog_(x) + (1.f-r.x)*clog_(1.f-x)));
            ly = scale * (-(r.y*clog_(y) + (1.f-r.y)*clog_(1.f-y)));
            float dw = fabsf(vw - r.z);
            lw = scale * (dw < 1.f ? 0.5f*dw*dw : dw - 0.5f);
            float dh = fabsf(vh - r.w);
            lh = scale * (dh < 1.f ? 0.5f*dh*dh : dh - 0.5f);
            lc = -clog_(conf);
        } else if (!ignore){
            lc = 0.5f * (-clog_(1.0f - conf));
        }
    }

    // ---- block reduction: wave shuffle, then cross-wave via LDS, plain stores ----
    #pragma unroll
    for (int off = 32; off > 0; off >>= 1){
        lx += __shfl_down(lx, off);
        ly += __shfl_down(ly, off);
        lw += __shfl_down(lw, off);
        lh += __shfl_down(lh, off);
        lc += __shfl_down(lc, off);
        lt += __shfl_down(lt, off);
    }
    __shared__ float s_red[4*6];
    if ((tid & 63) == 0){
        int wv = tid >> 6;
        s_red[wv*6+0] = lx; s_red[wv*6+1] = ly; s_red[wv*6+2] = lw;
        s_red[wv*6+3] = lh; s_red[wv*6+4] = lc; s_red[wv*6+5] = lt;
    }
    __syncthreads();
    if (tid < 6){
        float v = s_red[tid] + s_red[6+tid] + s_red[12+tid] + s_red[18+tid];
        partials[tid*NBLK + bid] = v;          // block-unique slot, no atomics
    }
    if (yb == 0 && tid == 0) counts[b] = nb;
}

// ---------------- Kernel 2: final reduce over 736 blocks + n_obj + output ----------------
__global__ __launch_bounds__(256) void finalize_k(
    const float* __restrict__ partials,
    const int*   __restrict__ counts,
    float*       __restrict__ out)
{
    int tid = threadIdx.x;
    float loc[6] = {0,0,0,0,0,0};
    for (int k = tid; k < NBLK; k += 256){
        #pragma unroll
        for (int j = 0; j < 6; ++j) loc[j] += partials[j*NBLK + k];
    }
    float nloc = (tid < BS) ? (float)counts[tid] : 0.f;

    #pragma unroll
    for (int off = 32; off > 0; off >>= 1){
        #pragma unroll
        for (int j = 0; j < 6; ++j) loc[j] += __shfl_down(loc[j], off);
        nloc += __shfl_down(nloc, off);
    }
    __shared__ float s_red[4*7];
    if ((tid & 63) == 0){
        int wv = tid >> 6;
        #pragma unroll
        for (int j = 0; j < 6; ++j) s_red[wv*7+j] = loc[j];
        s_red[wv*7+6] = nloc;
    }
    __syncthreads();
    if (tid == 0){
        float s[7];
        #pragma unroll
        for (int j = 0; j < 7; ++j)
            s[j] = s_red[j] + s_red[7+j] + s_red[14+j] + s_red[21+j];
        float n = s[6];
        float inv = (n > 0.f) ? (1.0f / n) : 0.0f;
        float lx = s[0]*inv, ly = s[1]*inv, lw = s[2]*inv, lh = s[3]*inv;
        float lconf = s[4]*inv;
        float ltcls = (n > 0.f) ? s[5]*inv : 0.0f;
        out[0] = lx + ly + lw + lh + lconf + ltcls;
        out[1] = lx;
        out[2] = ly;
        out[3] = lw;
        out[4] = lh;
        out[5] = lconf;
        out[6] = ltcls;
    }
}

extern "C" void kernel_launch(void* const* d_in, const int* in_sizes, int n_in,
                              void* d_out, int out_size, void* d_ws, size_t ws_size,
                              hipStream_t stream) {
    const float* input   = (const float*)d_in[0];
    const float* targets = (const float*)d_in[1];
    float* out = (float*)d_out;

    // ws layout: [0 .. 6*NBLK*4) partials | then counts[32]
    float* partials = (float*)d_ws;
    int*   counts   = (int*)((char*)d_ws + 6*NBLK*sizeof(float));

    dim3 grid(BS, YBLK);
    yolo_main<<<grid, dim3(256), 0, stream>>>(input, targets, partials, counts);
    finalize_k<<<1, dim3(256), 0, stream>>>(partials, counts, out);
}